// Round 13
// baseline (110.423 us; speedup 1.0000x reference)
//
#include <hip/hip_runtime.h>
#include <hip/hip_bf16.h>

typedef __attribute__((ext_vector_type(8))) short bf16x8;
typedef __attribute__((ext_vector_type(4))) float f32x4;
typedef __attribute__((ext_vector_type(4))) unsigned short u16x4;
typedef unsigned short u16;

#define M_DIM 50176
#define N_DIM 768
#define K_DIM 768
#define XB_ELEMS ((size_t)M_DIM * K_DIM)

__device__ __forceinline__ u16 f2bf(float f) {
    __hip_bfloat16 h = __float2bfloat16(f);
    return *reinterpret_cast<u16*>(&h);
}

__device__ __forceinline__ void gld_lds16(const void* g, void* l) {
    __builtin_amdgcn_global_load_lds(
        (const __attribute__((address_space(1))) unsigned int*)g,
        (__attribute__((address_space(3))) unsigned int*)l, 16, 0, 0);
}

// ---------------- Kernel 0: convert X f32 -> bf16 ----------------
// Normal (cached) stores: Xb (77 MB) stays L2/L3-resident for gemm_bf16's
// reads; L3 budget X(154)+Xb(77)+Bw(1.2) = 232 MB < 256 MB (Y is NT'd out).
__global__ __launch_bounds__(256)
void cvt_x(const float* __restrict__ X, u16* __restrict__ Xb) {
    const size_t n8 = XB_ELEMS / 8;
    for (size_t i = (size_t)blockIdx.x * blockDim.x + threadIdx.x; i < n8;
         i += (size_t)gridDim.x * blockDim.x) {
        const float4* src = (const float4*)(X + i * 8);
        float4 a = src[0], b = src[1];
        u16x4 lo, hi;
        lo.x = f2bf(a.x); lo.y = f2bf(a.y); lo.z = f2bf(a.z); lo.w = f2bf(a.w);
        hi.x = f2bf(b.x); hi.y = f2bf(b.y); hi.z = f2bf(b.z); hi.w = f2bf(b.w);
        u16x4* dst = (u16x4*)(Xb + i * 8);
        dst[0] = lo;
        dst[1] = hi;
    }
}

// ---------------- Kernel 1: fold weights ----------------
__global__ void fold_weights(const float* __restrict__ qkv_w,
                             const float* __restrict__ qkv_b,
                             const float* __restrict__ proj_w,
                             const float* __restrict__ proj_b,
                             const float* __restrict__ pe,
                             u16* __restrict__ Bw, float* __restrict__ bias) {
    const int o = blockIdx.x;
    const int t = threadIdx.x;
    __shared__ float wv[16];
    __shared__ float bv4[4];
    __shared__ float red[4];
    if (t < 16) wv[t] = qkv_w[32 + t];
    if (t < 4)  bv4[t] = qkv_b[8 + t];
    __syncthreads();
    const float* Prow = proj_w + o * 768;
    float s = 0.f;
    for (int c = t; c < 768; c += 256) {
        int g4 = c & ~3, j = c & 3;
        float af = Prow[g4 + 0] * wv[0 * 4 + j] + Prow[g4 + 1] * wv[1 * 4 + j] +
                   Prow[g4 + 2] * wv[2 * 4 + j] + Prow[g4 + 3] * wv[3 * 4 + j];
        Bw[o * 768 + c] = f2bf(af);
        s += af * pe[c];
        s += Prow[c] * bv4[j];
    }
    #pragma unroll
    for (int off = 32; off; off >>= 1) s += __shfl_down(s, off, 64);
    if ((t & 63) == 0) red[t >> 6] = s;
    __syncthreads();
    if (t == 0) bias[o] = red[0] + red[1] + red[2] + red[3] + proj_b[o];
}

// ---------------- Kernel 2 (fast path): pure-bf16 GEMM ----------------
// Y[m,o] = sum_c Xb[m,c] * Bw[o,c] + bias[o]
// m97 shape (R11-proven <86 us profiled): 128x128 tile, BK=64, 4 waves (2x2),
// SINGLE-buffered swizzled LDS (32 KiB), both operands via global_load_lds.
// 4 blocks/CU. Epilogue: R12-proven dense-LDS transpose, split into TWO 32 KiB
// half-tile passes so LDS stays 32 KiB. NT stores keep Y out of L3.
__global__ __launch_bounds__(256, 4)
void gemm_bf16(const u16* __restrict__ Xb, const u16* __restrict__ Bw,
               const float* __restrict__ bias, float* __restrict__ Y) {
    // XCD-aware bijective swizzle: 2352 blocks = 8 * 294
    const int b = blockIdx.x;
    const int bid = (b & 7) * 294 + (b >> 3);
    const int mt = bid / 6, nt = bid - mt * 6;
    const int m0 = mt * 128, n0 = nt * 128;

    const int tid = threadIdx.x;
    const int lane = tid & 63;
    const int w = tid >> 6;
    const int wm = w >> 1, wn = w & 1;

    // 32 KiB pool: As(16K)+Bs(16K) during K-loop; 64x128 f32 tile in epilogue.
    __shared__ __align__(16) char smem[32768];
    u16*   As   = (u16*)smem;
    u16*   Bs   = (u16*)(smem + 16384);
    float* pool = (float*)smem;

    f32x4 acc[4][4];
    #pragma unroll
    for (int i = 0; i < 4; ++i)
        #pragma unroll
        for (int j = 0; j < 4; ++j)
            acc[i][j] = (f32x4){0.f, 0.f, 0.f, 0.f};

    const int bg = lane & 7;

    // stage a 128x64 bf16 tile from row-major src (ld=K_DIM) into swizzled LDS
    auto stage = [&](const u16* srcbase, u16* lds, int k0) {
        #pragma unroll
        for (int j = 0; j < 4; ++j) {
            int rowbase = j * 32 + w * 8;
            int row = rowbase + (lane >> 3);
            const char* src = (const char*)srcbase + ((long)row * K_DIM + k0) * 2 +
                              ((bg * 16) ^ ((row & 7) << 4));
            gld_lds16(src, (void*)&lds[rowbase * 64]);
        }
    };

    auto compute = [&]() {
        #pragma unroll
        for (int h = 0; h < 2; ++h) {
            bf16x8 av[4], bv_[4];
            #pragma unroll
            for (int mf = 0; mf < 4; ++mf) {
                int r = wm * 64 + mf * 16 + (lane & 15);
                int pb = (h * 64 + ((lane >> 4) << 4)) ^ ((r & 7) << 4);
                av[mf] = *(const bf16x8*)&As[r * 64 + (pb >> 1)];
            }
            #pragma unroll
            for (int nf = 0; nf < 4; ++nf) {
                int r = wn * 64 + nf * 16 + (lane & 15);
                int pb = (h * 64 + ((lane >> 4) << 4)) ^ ((r & 7) << 4);
                bv_[nf] = *(const bf16x8*)&Bs[r * 64 + (pb >> 1)];
            }
            __builtin_amdgcn_s_setprio(1);
            #pragma unroll
            for (int mf = 0; mf < 4; ++mf)
                #pragma unroll
                for (int nf = 0; nf < 4; ++nf)
                    acc[mf][nf] = __builtin_amdgcn_mfma_f32_16x16x32_bf16(
                        av[mf], bv_[nf], acc[mf][nf], 0, 0, 0);
            __builtin_amdgcn_s_setprio(0);
        }
    };

    const u16* Abase = Xb + (long)m0 * K_DIM;
    const u16* Bbase = Bw + (long)n0 * K_DIM;

    // ---- prologue: stage tile 0 ----
    stage(Abase, As, 0);
    stage(Bbase, Bs, 0);
    __syncthreads();            // drains the 8 gld_lds

    const int NT = K_DIM / 64;  // 12
    #pragma unroll 1
    for (int t = 0; t < NT - 1; ++t) {
        compute();
        __syncthreads();        // all waves done reading As/Bs
        stage(Abase, As, (t + 1) * 64);
        stage(Bbase, Bs, (t + 1) * 64);
        __syncthreads();        // staging visible
    }
    compute();                  // tile 11
    __syncthreads();            // As/Bs dead -> pool reusable

    // ---- epilogue: two 64-row half-tiles through LDS, dense 16B NT stores ----
    // C/D layout col=lane&15, row=(lane>>4)*4+reg. Wave wm covers rows wm*64..+63.
    const int colq = lane & 15;
    const int rowq = (lane >> 4) * 4;
    #pragma unroll
    for (int h = 0; h < 2; ++h) {
        if (wm == h) {
            #pragma unroll
            for (int nf = 0; nf < 4; ++nf) {
                int col = wn * 64 + nf * 16 + colq;
                float bi = bias[n0 + col];
                #pragma unroll
                for (int mf = 0; mf < 4; ++mf) {
                    #pragma unroll
                    for (int r = 0; r < 4; ++r) {
                        int rl = mf * 16 + rowq + r;               // 0..63 local
                        int colS = col ^ (((rl >> 2) & 1) << 4);   // 2-way max (free)
                        pool[rl * 128 + colS] = acc[mf][nf][r] + bi;
                    }
                }
            }
        }
        __syncthreads();
        #pragma unroll
        for (int i = 0; i < 8; ++i) {
            int chunk = i * 256 + tid;     // 0..2047
            int rl = chunk >> 5;           // 0..63
            int g = chunk & 31;            // float4 granule in row
            int gs = g ^ (((rl >> 2) & 1) << 2);
            f32x4 v = *(const f32x4*)&pool[rl * 128 + gs * 4];
            __builtin_nontemporal_store(v,
                (f32x4*)&Y[(long)(m0 + h * 64 + rl) * N_DIM + n0 + g * 4]);
        }
        if (h == 0) __syncthreads();       // pool reuse guard
    }
}

// ---------------- Kernel 2 (fallback, R12 winner): f32-A GEMM ----------------
__global__ __launch_bounds__(256, 2)
void gemm_fused(const float* __restrict__ X, const u16* __restrict__ Bw,
                const float* __restrict__ bias, float* __restrict__ Y) {
    const int b = blockIdx.x;
    const int bid = (b & 7) * 294 + (b >> 3);
    const int mt = bid / 6, nt = bid - mt * 6;
    const int m0 = mt * 128, n0 = nt * 128;

    const int tid = threadIdx.x;
    const int lane = tid & 63;
    const int w = tid >> 6;
    const int wm = w >> 1, wn = w & 1;

    __shared__ __align__(16) float pool[16384];
    u16 (*As)[128 * 64] = (u16(*)[128 * 64])pool;
    u16 (*Bs)[128 * 64] = (u16(*)[128 * 64])((char*)pool + 32768);

    f32x4 acc[4][4];
    #pragma unroll
    for (int i = 0; i < 4; ++i)
        #pragma unroll
        for (int j = 0; j < 4; ++j)
            acc[i][j] = (f32x4){0.f, 0.f, 0.f, 0.f};

    const int arow = tid >> 4;
    const int agg  = tid & 15;
    const int bg = lane & 7;

    float4 preA[8], preB[8];

    auto load_a = [&](float4 (&p)[8], int k0) {
        const float4* src = (const float4*)(X + (long)m0 * K_DIM + k0);
        #pragma unroll
        for (int i = 0; i < 8; ++i) {
            int r = arow + 16 * i;
            p[i] = src[(long)r * (K_DIM / 4) + agg];
        }
    };

    auto write_a = [&](int buf, const float4 (&p)[8]) {
        #pragma unroll
        for (int i = 0; i < 8; ++i) {
            int r = arow + 16 * i;
            int pb = (agg * 8) ^ ((r & 7) << 4);
            u16x4 hv;
            hv.x = f2bf(p[i].x);
            hv.y = f2bf(p[i].y);
            hv.z = f2bf(p[i].z);
            hv.w = f2bf(p[i].w);
            *(u16x4*)&As[buf][r * 64 + (pb >> 1)] = hv;
        }
    };

    auto stage_b = [&](int buf, int k0) {
        #pragma unroll
        for (int j = 0; j < 4; ++j) {
            int rowbase = j * 32 + w * 8;
            int row = rowbase + (lane >> 3);
            const char* src = (const char*)Bw + ((long)(n0 + row) * K_DIM + k0) * 2 +
                              ((bg * 16) ^ ((row & 7) << 4));
            gld_lds16(src, (void*)&Bs[buf][rowbase * 64]);
        }
    };

    auto compute = [&](int buf) {
        #pragma unroll
        for (int h = 0; h < 2; ++h) {
            bf16x8 av[4], bv_[4];
            #pragma unroll
            for (int mf = 0; mf < 4; ++mf) {
                int r = wm * 64 + mf * 16 + (lane & 15);
                int pb = (h * 64 + ((lane >> 4) << 4)) ^ ((r & 7) << 4);
                av[mf] = *(const bf16x8*)&As[buf][r * 64 + (pb >> 1)];
            }
            #pragma unroll
            for (int nf = 0; nf < 4; ++nf) {
                int r = wn * 64 + nf * 16 + (lane & 15);
                int pb = (h * 64 + ((lane >> 4) << 4)) ^ ((r & 7) << 4);
                bv_[nf] = *(const bf16x8*)&Bs[buf][r * 64 + (pb >> 1)];
            }
            __builtin_amdgcn_s_setprio(1);
            #pragma unroll
            for (int mf = 0; mf < 4; ++mf)
                #pragma unroll
                for (int nf = 0; nf < 4; ++nf)
                    acc[mf][nf] = __builtin_amdgcn_mfma_f32_16x16x32_bf16(
                        av[mf], bv_[nf], acc[mf][nf], 0, 0, 0);
            __builtin_amdgcn_s_setprio(0);
        }
    };

    load_a(preA, 0);
    stage_b(0, 0);
    load_a(preB, 64);
    write_a(0, preA);
    __syncthreads();

    const int NT = K_DIM / 64;
    #pragma unroll 1
    for (int t2 = 0; t2 < NT; t2 += 2) {
        if (t2 + 1 < NT) {
            write_a(1, preB);
            stage_b(1, (t2 + 1) * 64);
        }
        if (t2 + 2 < NT) load_a(preA, (t2 + 2) * 64);
        compute(0);
        __syncthreads();

        if (t2 + 2 < NT) {
            write_a(0, preA);
            stage_b(0, (t2 + 2) * 64);
        }
        if (t2 + 3 < NT) load_a(preB, (t2 + 3) * 64);
        compute(1);
        __syncthreads();
    }

    const int colq = lane & 15;
    const int rowq = (lane >> 4) * 4;
    #pragma unroll
    for (int nf = 0; nf < 4; ++nf) {
        int col = wn * 64 + nf * 16 + colq;
        float bi = bias[n0 + col];
        #pragma unroll
        for (int mf = 0; mf < 4; ++mf) {
            int rbase = wm * 64 + mf * 16 + rowq;
            #pragma unroll
            for (int r = 0; r < 4; ++r) {
                int row = rbase + r;
                int colS = col ^ (((row >> 2) & 1) << 4);
                pool[row * 128 + colS] = acc[mf][nf][r] + bi;
            }
        }
    }
    __syncthreads();

    #pragma unroll
    for (int i = 0; i < 16; ++i) {
        int chunk = i * 256 + tid;
        int row = chunk >> 5;
        int g = chunk & 31;
        int gs = g ^ (((row >> 2) & 1) << 2);
        f32x4 v = *(const f32x4*)&pool[row * 128 + gs * 4];
        __builtin_nontemporal_store(v,
            (f32x4*)&Y[(long)(m0 + row) * N_DIM + n0 + g * 4]);
    }
}

extern "C" void kernel_launch(void* const* d_in, const int* in_sizes, int n_in,
                              void* d_out, int out_size, void* d_ws, size_t ws_size,
                              hipStream_t stream) {
    const float* x      = (const float*)d_in[0];
    const float* qkv_w  = (const float*)d_in[1];
    const float* qkv_b  = (const float*)d_in[2];
    const float* proj_w = (const float*)d_in[3];
    const float* proj_b = (const float*)d_in[4];
    const float* pe     = (const float*)d_in[5];
    float* y = (float*)d_out;

    const size_t xb_bytes   = XB_ELEMS * 2;                    // 77.07 MB
    const size_t bw_bytes   = (size_t)N_DIM * K_DIM * 2;       // 1.18 MB
    const size_t bias_bytes = N_DIM * sizeof(float);

    if (ws_size >= xb_bytes + bw_bytes + bias_bytes) {
        u16*   Xb   = (u16*)d_ws;
        u16*   Bw   = (u16*)((char*)d_ws + xb_bytes);
        float* bias = (float*)((char*)d_ws + xb_bytes + bw_bytes);
        cvt_x<<<4096, 256, 0, stream>>>(x, Xb);
        fold_weights<<<768, 256, 0, stream>>>(qkv_w, qkv_b, proj_w, proj_b, pe, Bw, bias);
        gemm_bf16<<<(M_DIM / 128) * (N_DIM / 128), 256, 0, stream>>>(Xb, Bw, bias, y);
    } else {
        u16*   Bw   = (u16*)d_ws;
        float* bias = (float*)((char*)d_ws + bw_bytes);
        fold_weights<<<768, 256, 0, stream>>>(qkv_w, qkv_b, proj_w, proj_b, pe, Bw, bias);
        gemm_fused<<<(M_DIM / 128) * (N_DIM / 128), 256, 0, stream>>>(x, Bw, bias, y);
    }
}